// Round 1
// baseline (514.564 us; speedup 1.0000x reference)
//
#include <hip/hip_runtime.h>

#define N_FEAT   512
#define N_PAIRS  130816   // 512*511/2
#define BROWS    4
#define VEC      4
#define TPB      256
#define PAIRS_PER_BLOCK (TPB * VEC)   // 1024

__global__ __launch_bounds__(TPB) void widelayer_kernel(
    const float* __restrict__ x,
    const float* __restrict__ w,
    float* __restrict__ out)
{
    __shared__ float xs[BROWS][N_FEAT];
    const int tid   = threadIdx.x;
    const int rbase = blockIdx.y * BROWS;

    // Stage BROWS rows of x (BROWS*512 floats = 512 float4) into LDS, 2 per thread.
    const float4* xv  = (const float4*)(x + (long long)rbase * N_FEAT);
    float4*       xsv = (float4*)&xs[0][0];
#pragma unroll
    for (int k = 0; k < (BROWS * N_FEAT / 4) / TPB; ++k)
        xsv[tid + k * TPB] = xv[tid + k * TPB];
    __syncthreads();

    const int p0 = blockIdx.x * PAIRS_PER_BLOCK + tid * VEC;
    if (p0 >= N_PAIRS) return;   // N_PAIRS % 4 == 0 -> threads are all-in or all-out

    // Closed-form p -> (i, j):  f(i) = i*(1023 - i)/2 pairs precede row i.
    // Solve i^2 - 1023 i + 2p = 0  ->  i = (1023 - sqrt(1023^2 - 8p)) / 2
    double disc = 1023.0 * 1023.0 - 8.0 * (double)p0;
    int i = (int)((1023.0 - sqrt(disc)) * 0.5);
    if (i < 0) i = 0;
    if (i > 510) i = 510;
    // integer fixups (at most 1-2 steps)
    while ((((long long)(i + 1)) * (1023 - (i + 1))) / 2 <= p0 && i < 510) ++i;
    while ((((long long)i) * (1023 - i)) / 2 > p0) --i;
    const long long fi = (((long long)i) * (1023 - i)) / 2;
    int j = i + 1 + (int)(p0 - fi);

    int ii[VEC], jj[VEC];
    int ci = i, cj = j;
#pragma unroll
    for (int k = 0; k < VEC; ++k) {
        ii[k] = ci; jj[k] = cj;
        ++cj;
        if (cj == N_FEAT) { ++ci; cj = ci + 1; }
    }

    const float4 wv = *(const float4*)(w + p0);
    const float wk[VEC] = {wv.x, wv.y, wv.z, wv.w};

#pragma unroll
    for (int r = 0; r < BROWS; ++r) {
        float4 o;
        float* op = (float*)&o;
#pragma unroll
        for (int k = 0; k < VEC; ++k)
            op[k] = (xs[r][ii[k]] * xs[r][jj[k]]) * wk[k];
        *(float4*)(out + (long long)(rbase + r) * N_PAIRS + p0) = o;
    }
}

extern "C" void kernel_launch(void* const* d_in, const int* in_sizes, int n_in,
                              void* d_out, int out_size, void* d_ws, size_t ws_size,
                              hipStream_t stream) {
    const float* x = (const float*)d_in[0];
    const float* w = (const float*)d_in[1];
    float* out = (float*)d_out;

    const int batch = in_sizes[0] / N_FEAT;   // 1024
    dim3 grid((N_PAIRS + PAIRS_PER_BLOCK - 1) / PAIRS_PER_BLOCK, batch / BROWS);
    widelayer_kernel<<<grid, TPB, 0, stream>>>(x, w, out);
}